// Round 4
// baseline (100.439 us; speedup 1.0000x reference)
//
#include <hip/hip_runtime.h>
#include <math.h>

// Problem constants (from reference)
#define BB 8
#define HH 1024
#define DD 4
#define TI 16            // i-rows per block
#define NJC 8            // j-chunks
#define JC (HH / NJC)    // 128 j per block
#define INV2PI 0.15915494309189535f

// ws layout: float4 partial[NJC][BB][HH] = 1 MB

__global__ __launch_bounds__(256, 8) void kuramoto_partial(
    const float* __restrict__ theta, const float* __restrict__ A,
    const float* __restrict__ alpha, float* __restrict__ ws)
{
    const int blk = blockIdx.x;          // ((b*64 + it)*NJC + jc)
    const int jc  = blk & (NJC - 1);
    const int it  = (blk >> 3) & 63;
    const int b   = blk >> 9;
    const int i0  = it * TI;
    const int j0  = jc * JC;
    const int t   = threadIdx.x;
    const int ti  = t >> 4;              // 0..15
    const int tj  = t & 15;              // 0..15

    __shared__ float sAT[JC][TI + 1];    // A[b, j0+r, i0+c] transposed (8.7 KB)

    const float* Ab = A + (size_t)b * HH * HH;

    // stage transposed A tile: 128 rows x 16 cols, coalesced float4 loads,
    // scalar LDS stores (bank pattern 17r+c: exactly 2 lanes/bank = free)
    {
        const int r = t >> 2;            // 0..63
        const int c = (t & 3) * 4;       // 0,4,8,12
        #pragma unroll
        for (int rr = 0; rr < JC; rr += 64) {
            const int row = rr + r;
            const float4 v = *(const float4*)&Ab[(size_t)(j0 + row) * HH + i0 + c];
            sAT[row][c + 0] = v.x;
            sAT[row][c + 1] = v.y;
            sAT[row][c + 2] = v.z;
            sAT[row][c + 3] = v.w;
        }
    }

    // theta_i, prescaled to revolutions (v_sin_f32 takes revolutions)
    float4 thi = ((const float4*)theta)[(size_t)b * HH + i0 + ti];
    thi.x *= INV2PI; thi.y *= INV2PI; thi.z *= INV2PI; thi.w *= INV2PI;

    __syncthreads();   // the only barrier

    const float4* Arow4  = (const float4*)(Ab    + (size_t)(i0 + ti) * HH + j0);
    const float4* alrow4 = (const float4*)(alpha + (size_t)(i0 + ti) * HH + j0);
    const float4* th4    = (const float4*)theta + (size_t)b * HH + j0;  // L1-resident (2 KB)

    float a0 = 0.f, a1 = 0.f, a2 = 0.f, a3 = 0.f;

#define DO_J(k, thv)                                                        \
    {                                                                       \
        const float adk  = (&ad.x)[k];                                      \
        const float alk  = (&al.x)[k] * INV2PI;                             \
        const float at   = sAT[4 * q + k][ti];   /* 2-way alias = free */   \
        const float alat = fmaxf(adk + at, 0.0f); /* 0.5 folded into final */\
        const float w0 = thi.x + alk, w1 = thi.y + alk;                     \
        const float w2 = thi.z + alk, w3 = thi.w + alk;                     \
        a0 += alat * __builtin_amdgcn_sinf(thv.x * INV2PI - w0);            \
        a1 += alat * __builtin_amdgcn_sinf(thv.y * INV2PI - w1);            \
        a2 += alat * __builtin_amdgcn_sinf(thv.z * INV2PI - w2);            \
        a3 += alat * __builtin_amdgcn_sinf(thv.w * INV2PI - w3);            \
    }

    #pragma unroll
    for (int s = 0; s < JC / 64; ++s) {          // 2 iters, 4 j's each
        const int q = tj + 16 * s;
        const float4 ad = Arow4[q];              // coalesced dwordx4 (HBM stream)
        const float4 al = alrow4[q];             // coalesced dwordx4 (L3-resident)
        const float4 t0 = th4[4 * q + 0];        // L1 hits
        const float4 t1 = th4[4 * q + 1];
        const float4 t2 = th4[4 * q + 2];
        const float4 t3 = th4[4 * q + 3];
        DO_J(0, t0)
        DO_J(1, t1)
        DO_J(2, t2)
        DO_J(3, t3)
    }
#undef DO_J

    // reduce over the 16 tj lanes (ti groups are lane-contiguous in a wave)
    #pragma unroll
    for (int off = 8; off >= 1; off >>= 1) {
        a0 += __shfl_down(a0, off, 16);
        a1 += __shfl_down(a1, off, 16);
        a2 += __shfl_down(a2, off, 16);
        a3 += __shfl_down(a3, off, 16);
    }

    if (tj == 0) {
        float4 r; r.x = a0; r.y = a1; r.z = a2; r.w = a3;
        ((float4*)ws)[((size_t)jc * BB + b) * HH + i0 + ti] = r;
    }
}

__global__ __launch_bounds__(256) void kuramoto_final(
    const float* __restrict__ theta, const float* __restrict__ gamma,
    const float* __restrict__ omega, const float* __restrict__ kappa,
    const float* __restrict__ ws, float* __restrict__ out)
{
    const int idx = blockIdx.x * 256 + threadIdx.x;   // (b,i) flat, 8192 total
    const int i   = idx & (HH - 1);
    const float4* w4 = (const float4*)ws;

    float4 p = w4[idx];
    #pragma unroll
    for (int jc = 1; jc < NJC; ++jc) {
        const float4 q = w4[(size_t)jc * BB * HH + idx];
        p.x += q.x; p.y += q.y; p.z += q.z; p.w += q.w;
    }

    const float4 th = ((const float4*)theta)[idx];
    const float4 om = ((const float4*)omega)[i];
    const float4 kp = ((const float4*)kappa)[i];
    const float  g  = gamma[idx];
    const float  inv = 0.5f / HH;   // K_COUP=1, DT=1, 0.5 from symmetrization fold

    float4 o;
    o.x = th.x + om.x + p.x * inv + kp.x * (g - th.x);
    o.y = th.y + om.y + p.y * inv + kp.y * (g - th.y);
    o.z = th.z + om.z + p.z * inv + kp.z * (g - th.z);
    o.w = th.w + om.w + p.w * inv + kp.w * (g - th.w);
    ((float4*)out)[idx] = o;
}

extern "C" void kernel_launch(void* const* d_in, const int* in_sizes, int n_in,
                              void* d_out, int out_size, void* d_ws, size_t ws_size,
                              hipStream_t stream) {
    const float* theta = (const float*)d_in[0];
    const float* gamma = (const float*)d_in[1];
    const float* A     = (const float*)d_in[2];
    const float* omega = (const float*)d_in[3];
    const float* kappa = (const float*)d_in[4];
    const float* alpha = (const float*)d_in[5];
    float* out = (float*)d_out;
    float* ws  = (float*)d_ws;

    hipLaunchKernelGGL(kuramoto_partial, dim3(BB * (HH / TI) * NJC), dim3(256), 0, stream,
                       theta, A, alpha, ws);
    hipLaunchKernelGGL(kuramoto_final, dim3(BB * HH / 256), dim3(256), 0, stream,
                       theta, gamma, omega, kappa, ws, out);
}